// Round 1
// baseline (71.032 us; speedup 1.0000x reference)
//
#include <hip/hip_runtime.h>
#include <hip/hip_bf16.h>

#define E 1024
#define F 12

__global__ __launch_bounds__(256) void ffq_kernel(
    const float* __restrict__ x,
    const float* __restrict__ W1,
    const float* __restrict__ b1,
    const float* __restrict__ theta,
    const float* __restrict__ W2,
    const float* __restrict__ b2,
    float* __restrict__ out,
    int nrows)
{
    const int tid  = threadIdx.x;
    const int lane = tid & 63;
    const int wave = tid >> 6;

    // ---- persistent, register-resident weights (read once per block) ----
    float w1[F][4];
#pragma unroll
    for (int f = 0; f < F; ++f) {
        const float4 wv = *reinterpret_cast<const float4*>(W1 + f * E + tid * 4);
        w1[f][0] = wv.x; w1[f][1] = wv.y; w1[f][2] = wv.z; w1[f][3] = wv.w;
    }
    float w2[4][F];
#pragma unroll
    for (int j = 0; j < 4; ++j) {
        const int e = tid * 4 + j;
#pragma unroll
        for (int f = 0; f < F; ++f) w2[j][f] = W2[e * F + f];
    }
    float bias2[4];
#pragma unroll
    for (int j = 0; j < 4; ++j) bias2[j] = b2[tid * 4 + j];

    float b1r = 0.f, thr = 0.f;
    if (tid < F) { b1r = b1[tid]; thr = theta[tid]; }

    __shared__ float red[4][F];
    __shared__ float qsh[F];

    // ---- grid-stride over the 16384 rows ----
    for (int row = blockIdx.x; row < nrows; row += gridDim.x) {
        const float4 xv = *reinterpret_cast<const float4*>(x + (size_t)row * E + tid * 4);

        float part[F];
#pragma unroll
        for (int f = 0; f < F; ++f) {
            part[f] = fmaf(xv.x, w1[f][0],
                      fmaf(xv.y, w1[f][1],
                      fmaf(xv.z, w1[f][2], xv.w * w1[f][3])));
        }

        // intra-wave butterfly reduction across 64 lanes
#pragma unroll
        for (int off = 32; off >= 1; off >>= 1) {
#pragma unroll
            for (int f = 0; f < F; ++f)
                part[f] += __shfl_xor(part[f], off, 64);
        }
        if (lane == 0) {
#pragma unroll
            for (int f = 0; f < F; ++f) red[wave][f] = part[f];
        }
        __syncthreads();

        if (tid < F) {
            float d = red[0][tid] + red[1][tid] + red[2][tid] + red[3][tid] + b1r;
            d = fmaxf(d, 0.0f) + thr;   // relu then +theta
            qsh[tid] = cosf(d);
        }
        __syncthreads();

        float q[F];
#pragma unroll
        for (int f = 0; f < F; ++f) q[f] = qsh[f];

        float4 o;
#pragma unroll
        for (int j = 0; j < 4; ++j) {
            float acc = bias2[j];
#pragma unroll
            for (int f = 0; f < F; ++f) acc = fmaf(q[f], w2[j][f], acc);
            (&o.x)[j] = acc;
        }
        *reinterpret_cast<float4*>(out + (size_t)row * E + tid * 4) = o;

        __syncthreads();  // protect red/qsh from next-iteration overwrite
    }
}

extern "C" void kernel_launch(void* const* d_in, const int* in_sizes, int n_in,
                              void* d_out, int out_size, void* d_ws, size_t ws_size,
                              hipStream_t stream)
{
    const float* x     = (const float*)d_in[0];
    const float* W1    = (const float*)d_in[1];
    const float* b1    = (const float*)d_in[2];
    const float* theta = (const float*)d_in[3];
    const float* W2    = (const float*)d_in[4];
    const float* b2    = (const float*)d_in[5];
    float* out = (float*)d_out;

    const int nrows = in_sizes[0] / E;   // B*S = 16384
    const int grid  = 2048;              // persistent blocks; weights read once each

    ffq_kernel<<<grid, 256, 0, stream>>>(x, W1, b1, theta, W2, b2, out, nrows);
}

// Round 2
// 43.167 us; speedup vs baseline: 1.6455x; 1.6455x over previous
//
#include <hip/hip_runtime.h>
#include <hip/hip_bf16.h>

#define E 1024
#define F 12

// DPP-based add: v += dpp(v). CTRL: 0x110|N = row_shr:N, 0x142 = row_bcast15,
// 0x143 = row_bcast31. bound_ctrl=true -> out-of-range lanes contribute 0.
template<int CTRL>
__device__ __forceinline__ float dpp_add(float v) {
    int x = __builtin_amdgcn_update_dpp(0, __float_as_int(v), CTRL, 0xf, 0xf, true);
    return v + __int_as_float(x);
}

// Full 64-lane sum; result valid in lane 63 only. Pure VALU pipe (no DS ops).
__device__ __forceinline__ float wave_sum_lane63(float v) {
    v = dpp_add<0x111>(v);  // row_shr:1
    v = dpp_add<0x112>(v);  // row_shr:2
    v = dpp_add<0x114>(v);  // row_shr:4
    v = dpp_add<0x118>(v);  // row_shr:8  -> lane 15 of each 16-row has row sum
    v = dpp_add<0x142>(v);  // row_bcast15 -> lane31 = lanes0-31, lane63 += lane47(row2)
    v = dpp_add<0x143>(v);  // row_bcast31 -> lane63 = full 64-lane sum
    return v;
}

__global__ __launch_bounds__(256) void ffq_kernel(
    const float* __restrict__ x,
    const float* __restrict__ W1,
    const float* __restrict__ b1,
    const float* __restrict__ theta,
    const float* __restrict__ W2,
    const float* __restrict__ b2,
    float* __restrict__ out,
    int nrows, int rows_per_block)
{
    const int tid  = threadIdx.x;
    const int lane = tid & 63;
    const int wave = tid >> 6;

    // ---- register-resident weights, read once per block ----
    float4 w1[F];                       // w1[f] = W1[f][4t..4t+3]
#pragma unroll
    for (int f = 0; f < F; ++f)
        w1[f] = *reinterpret_cast<const float4*>(W1 + f * E + tid * 4);

    float w2l[48];                      // W2[(4t+j)][f] = w2l[12j+f], 48 consecutive floats
#pragma unroll
    for (int k = 0; k < 12; ++k)
        *reinterpret_cast<float4*>(&w2l[4 * k]) =
            *reinterpret_cast<const float4*>(W2 + tid * 48 + 4 * k);

    const float4 bias2 = *reinterpret_cast<const float4*>(b2 + tid * 4);

    float b1r = 0.f, thr = 0.f;
    if (tid < F) { b1r = b1[tid]; thr = theta[tid]; }

    __shared__ float red[4][F];
    __shared__ __align__(16) float qsh[F];

    const int rstart = blockIdx.x * rows_per_block;
    const int rend   = min(rstart + rows_per_block, nrows);
    if (rstart >= rend) return;

    float4 xv = *reinterpret_cast<const float4*>(x + (size_t)rstart * E + tid * 4);
    float4 xnext;

    for (int row = rstart; row < rend; ++row) {
        // ---- phase 1: per-thread partial dots (48 FMA) ----
        float part[F];
#pragma unroll
        for (int f = 0; f < F; ++f) {
            part[f] = fmaf(xv.x, w1[f].x,
                      fmaf(xv.y, w1[f].y,
                      fmaf(xv.z, w1[f].z, xv.w * w1[f].w)));
        }

        // prefetch next row while the DPP chain runs
        if (row + 1 < rend)
            xnext = *reinterpret_cast<const float4*>(x + (size_t)(row + 1) * E + tid * 4);

        // ---- wave reduction on the VALU pipe (DPP), result in lane 63 ----
#pragma unroll
        for (int f = 0; f < F; ++f)
            part[f] = wave_sum_lane63(part[f]);

        if (lane == 63) {
#pragma unroll
            for (int f = 0; f < F; ++f) red[wave][f] = part[f];
        }
        __syncthreads();

        // ---- finisher: 12 lanes do bias + relu + theta + cos ----
        if (tid < F) {
            float d = red[0][tid] + red[1][tid] + red[2][tid] + red[3][tid] + b1r;
            qsh[tid] = cosf(fmaxf(d, 0.0f) + thr);
        }
        __syncthreads();

        // ---- phase 2: out[row][4t..4t+3] = q . W2 + b2 (broadcast LDS reads) ----
        float qf[12];
        *reinterpret_cast<float4*>(&qf[0]) = *reinterpret_cast<const float4*>(&qsh[0]);
        *reinterpret_cast<float4*>(&qf[4]) = *reinterpret_cast<const float4*>(&qsh[4]);
        *reinterpret_cast<float4*>(&qf[8]) = *reinterpret_cast<const float4*>(&qsh[8]);

        float4 o;
#pragma unroll
        for (int j = 0; j < 4; ++j) {
            float acc = (&bias2.x)[j];
#pragma unroll
            for (int f = 0; f < F; ++f) acc = fmaf(qf[f], w2l[12 * j + f], acc);
            (&o.x)[j] = acc;
        }
        *reinterpret_cast<float4*>(out + (size_t)row * E + tid * 4) = o;

        xv = xnext;
        // note: no 3rd barrier needed — red(i+1) writes happen only after all
        // threads passed barrier B(i) (post-finisher), and qsh(i+1) writes only
        // after barrier A(i+1), which follows every thread's qsh(i) read.
    }
}

extern "C" void kernel_launch(void* const* d_in, const int* in_sizes, int n_in,
                              void* d_out, int out_size, void* d_ws, size_t ws_size,
                              hipStream_t stream)
{
    const float* x     = (const float*)d_in[0];
    const float* W1    = (const float*)d_in[1];
    const float* b1    = (const float*)d_in[2];
    const float* theta = (const float*)d_in[3];
    const float* W2    = (const float*)d_in[4];
    const float* b2    = (const float*)d_in[5];
    float* out = (float*)d_out;

    const int nrows = in_sizes[0] / E;           // B*S = 16384
    const int grid  = 1024;                      // ~4 blocks/CU co-resident
    const int rpb   = (nrows + grid - 1) / grid; // 16 rows per block

    ffq_kernel<<<grid, 256, 0, stream>>>(x, W1, b1, theta, W2, b2, out, nrows, rpb);
}

// Round 4
// 36.468 us; speedup vs baseline: 1.9478x; 1.1837x over previous
//
#include <hip/hip_runtime.h>
#include <hip/hip_bf16.h>

#define E 1024
#define F 12
#define R 4   // rows per iteration

typedef float f32x4 __attribute__((ext_vector_type(4)));

// DPP add: v += dpp(v). 0x110|N = row_shr:N, 0x142 = row_bcast15, 0x143 = row_bcast31.
template<int CTRL>
__device__ __forceinline__ float dpp_add(float v) {
    int x = __builtin_amdgcn_update_dpp(0, __float_as_int(v), CTRL, 0xf, 0xf, true);
    return v + __int_as_float(x);
}

// Full 64-lane sum on the VALU pipe; result valid in lane 63.
__device__ __forceinline__ float wave_sum_lane63(float v) {
    v = dpp_add<0x111>(v);
    v = dpp_add<0x112>(v);
    v = dpp_add<0x114>(v);
    v = dpp_add<0x118>(v);
    v = dpp_add<0x142>(v);
    v = dpp_add<0x143>(v);
    return v;
}

__global__ __launch_bounds__(256, 2) void ffq_kernel(
    const float* __restrict__ x,
    const float* __restrict__ W1,
    const float* __restrict__ b1,
    const float* __restrict__ theta,
    const float* __restrict__ W2,
    const float* __restrict__ b2,
    float* __restrict__ out,
    int nrows, int rows_per_block)
{
    const int tid  = threadIdx.x;
    const int lane = tid & 63;
    const int wave = tid >> 6;

    // ---- register-resident weights (launch_bounds(256,2) => up to 256 VGPR) ----
    f32x4 w1[F];                      // W1[f][4t..4t+3]
#pragma unroll
    for (int f = 0; f < F; ++f)
        w1[f] = *reinterpret_cast<const f32x4*>(W1 + f * E + tid * 4);

    float w2l[48];                    // W2[(4t+j)][f] = w2l[12j+f]
#pragma unroll
    for (int k = 0; k < 12; ++k)
        *reinterpret_cast<f32x4*>(&w2l[4 * k]) =
            *reinterpret_cast<const f32x4*>(W2 + tid * 48 + 4 * k);

    const f32x4 bias2 = *reinterpret_cast<const f32x4*>(b2 + tid * 4);

    // finisher threads: t in [0,64), r = t>>4, f = t&15 (active if f<12)
    float b1r = 0.f, thr = 0.f;
    if (tid < 64 && (tid & 15) < F) { b1r = b1[tid & 15]; thr = theta[tid & 15]; }

    __shared__ __align__(16) float red[4][R][F];   // [wave][r][f]
    __shared__ __align__(16) float qsh[R][F];

    const int rstart = blockIdx.x * rows_per_block;
    const int rend   = min(rstart + rows_per_block, nrows);
    if (rstart >= rend) return;

    f32x4 xv[R], xn[R];
#pragma unroll
    for (int r = 0; r < R; ++r)
        if (rstart + r < rend)
            xv[r] = *reinterpret_cast<const f32x4*>(x + (size_t)(rstart + r) * E + tid * 4);

    for (int base = rstart; base < rend; base += R) {
        // ---- phase 1: partial dots for R rows (R*48 FMA) ----
        float part[R][F];
#pragma unroll
        for (int r = 0; r < R; ++r) {
#pragma unroll
            for (int f = 0; f < F; ++f) {
                part[r][f] = fmaf(xv[r].x, w1[f].x,
                             fmaf(xv[r].y, w1[f].y,
                             fmaf(xv[r].z, w1[f].z, xv[r].w * w1[f].w)));
            }
        }

        // prefetch next R rows; in flight across reduce + barriers + phase 2
#pragma unroll
        for (int r = 0; r < R; ++r)
            if (base + R + r < rend)
                xn[r] = *reinterpret_cast<const f32x4*>(x + (size_t)(base + R + r) * E + tid * 4);

        // ---- DPP wave reduction (VALU pipe), results in lane 63 ----
#pragma unroll
        for (int r = 0; r < R; ++r)
#pragma unroll
            for (int f = 0; f < F; ++f)
                part[r][f] = wave_sum_lane63(part[r][f]);

        if (lane == 63) {
#pragma unroll
            for (int r = 0; r < R; ++r) {
                f32x4 a = { part[r][0], part[r][1], part[r][2],  part[r][3] };
                f32x4 b = { part[r][4], part[r][5], part[r][6],  part[r][7] };
                f32x4 c = { part[r][8], part[r][9], part[r][10], part[r][11] };
                *reinterpret_cast<f32x4*>(&red[wave][r][0]) = a;
                *reinterpret_cast<f32x4*>(&red[wave][r][4]) = b;
                *reinterpret_cast<f32x4*>(&red[wave][r][8]) = c;
            }
        }
        __syncthreads();

        // ---- finisher: 48 parallel lanes (r = t>>4, f = t&15) ----
        if (tid < 64 && (tid & 15) < F) {
            const int r = tid >> 4, fi = tid & 15;
            if (base + r < rend) {
                float d = red[0][r][fi] + red[1][r][fi] + red[2][r][fi] + red[3][r][fi] + b1r;
                qsh[r][fi] = cosf(fmaxf(d, 0.0f) + thr);
            }
        }
        __syncthreads();

        // ---- phase 2: out[row][4t..4t+3] = q . W2 + b2, nontemporal store ----
#pragma unroll
        for (int r = 0; r < R; ++r) {
            if (base + r < rend) {
                float qf[F];
                *reinterpret_cast<f32x4*>(&qf[0]) = *reinterpret_cast<const f32x4*>(&qsh[r][0]);
                *reinterpret_cast<f32x4*>(&qf[4]) = *reinterpret_cast<const f32x4*>(&qsh[r][4]);
                *reinterpret_cast<f32x4*>(&qf[8]) = *reinterpret_cast<const f32x4*>(&qsh[r][8]);

                f32x4 o;
#pragma unroll
                for (int j = 0; j < 4; ++j) {
                    float acc = bias2[j];
#pragma unroll
                    for (int f = 0; f < F; ++f) acc = fmaf(qf[f], w2l[12 * j + f], acc);
                    o[j] = acc;
                }
                __builtin_nontemporal_store(o,
                    reinterpret_cast<f32x4*>(out + (size_t)(base + r) * E + tid * 4));
            }
        }

#pragma unroll
        for (int r = 0; r < R; ++r) xv[r] = xn[r];
        // no 3rd barrier: next red writes happen only after all threads passed
        // the post-finisher barrier; next qsh writes only after the next
        // pre-finisher barrier, which follows every thread's qsh read here.
    }
}

extern "C" void kernel_launch(void* const* d_in, const int* in_sizes, int n_in,
                              void* d_out, int out_size, void* d_ws, size_t ws_size,
                              hipStream_t stream)
{
    const float* x     = (const float*)d_in[0];
    const float* W1    = (const float*)d_in[1];
    const float* b1    = (const float*)d_in[2];
    const float* theta = (const float*)d_in[3];
    const float* W2    = (const float*)d_in[4];
    const float* b2    = (const float*)d_in[5];
    float* out = (float*)d_out;

    const int nrows = in_sizes[0] / E;           // B*S = 16384
    const int rpb   = 16;
    const int grid  = (nrows + rpb - 1) / rpb;   // 1024 blocks

    ffq_kernel<<<grid, 256, 0, stream>>>(x, W1, b1, theta, W2, b2, out, nrows, rpb);
}